// Round 1
// 190.179 us; speedup vs baseline: 1.0326x; 1.0326x over previous
//
#include <hip/hip_runtime.h>
#include <math.h>

// Problem constants (fixed by the reference):
#define B_  4
#define C_  256     // in/out channels
#define CI_ 128     // inter channels (attention head dim D)
#define N_  4096    // H*W

typedef short s16x8  __attribute__((ext_vector_type(8)));    // 8 bf16 (4 VGPRs)
typedef float f32x4  __attribute__((ext_vector_type(4)));    // 16x16 accumulator
typedef float f32x16 __attribute__((ext_vector_type(16)));   // 32x32 accumulator

// fp32 -> bf16 (RNE)
__device__ inline ushort f2bf(float f) {
    unsigned int u = __float_as_uint(f);
    u += 0x7FFF + ((u >> 16) & 1);
    return (ushort)(u >> 16);
}
__device__ inline float bf2f(ushort u) {
    return __uint_as_float(((unsigned int)u) << 16);
}

// packed f32x2 -> bf16x2 (RNE), dst[15:0]=bf16(a), dst[31:16]=bf16(b)
__device__ inline unsigned pkbf(float a, float b) {
    unsigned r;
    asm("v_cvt_pk_bf16_f32 %0, %1, %2" : "=v"(r) : "v"(a), "v"(b));
    return r;
}
// v_permlane32_swap_b32 x, y:
//   new x[32+i] = old y[i];  new y[i] = old x[32+i]   (i = 0..31)
__device__ inline void plswap(unsigned &x, unsigned &y) {
    asm volatile("v_permlane32_swap_b32 %0, %1" : "+v"(x), "+v"(y));
}

// LDS-only workgroup sync: waits DS-queue drain (lgkmcnt) + rendezvous,
// WITHOUT the vmcnt(0) drain __syncthreads() forces before s_barrier.
// In-flight global prefetch loads stay in flight across this sync; the
// compiler still auto-inserts the data-arrival vmcnt(N) before first USE
// of the loaded registers (at the LDS commit point). m139 recipe.
__device__ inline void block_sync_lds() {
    asm volatile("s_waitcnt lgkmcnt(0)" ::: "memory");
    __builtin_amdgcn_s_barrier();
    asm volatile("" ::: "memory");
}

// ---------------------------------------------------------------------------
// Weight cast: Wcat = [Wg;Wt;Wp] bf16 (384x256), Wobf bf16 (256x128),
// bcat = [bg;bt;bp] fp32 (384). Grid 512x256.
// ---------------------------------------------------------------------------
__global__ __launch_bounds__(256) void wcast_kernel(
    const float* __restrict__ Wg, const float* __restrict__ Wt,
    const float* __restrict__ Wp, const float* __restrict__ Wo,
    const float* __restrict__ bg, const float* __restrict__ bt,
    const float* __restrict__ bp,
    ushort* __restrict__ Wcat, ushort* __restrict__ Wobf,
    float* __restrict__ bcat)
{
    int i = blockIdx.x * 256 + threadIdx.x;
    if (i < 32768)       Wcat[i] = f2bf(Wg[i]);
    else if (i < 65536)  Wcat[i] = f2bf(Wt[i - 32768]);
    else if (i < 98304)  Wcat[i] = f2bf(Wp[i - 65536]);
    else if (i < 131072) Wobf[i - 98304] = f2bf(Wo[i - 98304]);
    if (i < 128)         bcat[i] = bg[i];
    else if (i < 256)    bcat[i] = bt[i - 128];
    else if (i < 384)    bcat[i] = bp[i - 256];
}

// ---------------------------------------------------------------------------
// x transpose+cast: x [B][C][N] fp32 -> xT [B][N][C] bf16. Tile 64c x 64n.
// ---------------------------------------------------------------------------
__global__ __launch_bounds__(256) void xt_kernel(
    const float* __restrict__ x, ushort* __restrict__ xT)
{
    __shared__ ushort Ls[64][72];
    const int b = blockIdx.z, c0 = blockIdx.y * 64, n0 = blockIdx.x * 64;
    const float* xb = x + ((size_t)b * C_ + c0) * N_ + n0;
    const int t = threadIdx.x;
    #pragma unroll
    for (int r = 0; r < 4; r++) {
        int idx = t + 256 * r;
        int c = idx >> 4, n4 = (idx & 15) * 4;
        float4 v = *(const float4*)&xb[(size_t)c * N_ + n4];
        ushort4 o;
        o.x = f2bf(v.x); o.y = f2bf(v.y); o.z = f2bf(v.z); o.w = f2bf(v.w);
        *(ushort4*)&Ls[c][n4] = o;
    }
    __syncthreads();
    ushort* xTb = xT + ((size_t)b * N_ + n0) * C_ + c0;
    #pragma unroll
    for (int r = 0; r < 2; r++) {
        int idx = t + 256 * r;
        int n = idx >> 3, c8 = (idx & 7) * 8;
        ushort tmp[8];
        #pragma unroll
        for (int u = 0; u < 8; u++) tmp[u] = Ls[c8 + u][n];
        *(uint4*)&xTb[(size_t)n * C_ + c8] = *(uint4*)tmp;
    }
}

// ---------------------------------------------------------------------------
// Fused projection GEMM (bf16 MFMA, 16x16x32). Grid (N/64, 6, B).
// ---------------------------------------------------------------------------
__global__ __launch_bounds__(256) void proj_kernel(
    const ushort* __restrict__ Wcat, const float* __restrict__ bcat,
    const ushort* __restrict__ xT,
    ushort* __restrict__ g, ushort* __restrict__ tht, ushort* __restrict__ pht)
{
    __shared__ ushort Ws[64][72];
    __shared__ ushort Xs[64][72];
    const int b = blockIdx.z, mt = blockIdx.y, n0 = blockIdx.x * 64;
    const int t = threadIdx.x, wv = t >> 6, lane = t & 63;
    const int g4 = lane >> 4, ln = lane & 15;
    const ushort* Wsrc = Wcat + (size_t)mt * 64 * C_;
    const ushort* Xsrc = xT + ((size_t)b * N_ + n0) * C_;

    f32x4 acc[4];
    #pragma unroll
    for (int i = 0; i < 4; i++) acc[i] = (f32x4){0.f, 0.f, 0.f, 0.f};

    for (int k0 = 0; k0 < C_; k0 += 64) {
        block_sync_lds();
        #pragma unroll
        for (int r = 0; r < 2; r++) {
            int idx = t + 256 * r;
            int row = idx >> 3, k8 = (idx & 7) * 8;
            *(uint4*)&Ws[row][k8] = *(const uint4*)&Wsrc[(size_t)row * C_ + k0 + k8];
            *(uint4*)&Xs[row][k8] = *(const uint4*)&Xsrc[(size_t)row * C_ + k0 + k8];
        }
        block_sync_lds();
        if (mt < 2) {
            #pragma unroll
            for (int kk = 0; kk < 2; kk++) {
                s16x8 aW = *(const s16x8*)&Ws[16 * wv + ln][32 * kk + 8 * g4];
                #pragma unroll
                for (int nt = 0; nt < 4; nt++) {
                    s16x8 bX = *(const s16x8*)&Xs[16 * nt + ln][32 * kk + 8 * g4];
                    acc[nt] = __builtin_amdgcn_mfma_f32_16x16x32_bf16(aW, bX, acc[nt], 0, 0, 0);
                }
            }
        } else {
            #pragma unroll
            for (int kk = 0; kk < 2; kk++) {
                s16x8 aX = *(const s16x8*)&Xs[16 * wv + ln][32 * kk + 8 * g4];
                #pragma unroll
                for (int ct = 0; ct < 4; ct++) {
                    s16x8 bW = *(const s16x8*)&Ws[16 * ct + ln][32 * kk + 8 * g4];
                    acc[ct] = __builtin_amdgcn_mfma_f32_16x16x32_bf16(aX, bW, acc[ct], 0, 0, 0);
                }
            }
        }
    }

    if (mt < 2) {
        ushort* ob = g + (size_t)b * CI_ * N_;
        #pragma unroll
        for (int r = 0; r < 4; r++) {
            int mloc = 16 * wv + 4 * g4 + r;
            float bi = bcat[mt * 64 + mloc];
            #pragma unroll
            for (int nt = 0; nt < 4; nt++)
                ob[(size_t)(mt * 64 + mloc) * N_ + n0 + 16 * nt + ln] = f2bf(acc[nt][r] + bi);
        }
    } else {
        ushort* ob = ((mt < 4) ? tht : pht) + (size_t)b * N_ * CI_;
        int cib = ((mt - 2) & 1) * 64;
        #pragma unroll
        for (int r = 0; r < 4; r++) {
            int nloc = 16 * wv + 4 * g4 + r;
            #pragma unroll
            for (int ct = 0; ct < 4; ct++) {
                float bi = bcat[mt * 64 + 16 * ct + ln];
                ob[(size_t)(n0 + nloc) * CI_ + cib + 16 * ct + ln] = f2bf(acc[ct][r] + bi);
            }
        }
    }
}

// ---------------------------------------------------------------------------
// MFMA flash attention, 32x32x16, T12 in-register softmax.
// Swapped QK^T: S^T = mfma(K_frag, Q_frag) so each lane holds the full
// P-row slice for its q = lane&31 in registers. exp + row-sum in-register
// (no-max softmax, no P LDS round-trip, no ones-MFMA). PV A-fragments
// built via v_cvt_pk_bf16_f32 + v_permlane32_swap_b32 (m214 v22 recipe).
// Q fragments loaded straight from global (no Q staging). K/V tiles
// double-staged via register prefetch + LDS-only syncs.
// ---------------------------------------------------------------------------
#define SQK 136   // K row stride (bf16), 272 B -> 2-way max on b128 reads
#define SPV 72    // V^T row stride (bf16), 144 B
#define JCHUNK 1024

// Build two PV A-fragments (k-slots j0..15 / j16..31 of one 32-j S^T tile)
// from the 16 in-lane scores. Returns bf16-rounded partial row-sum (matches
// the previous ones-MFMA-over-bf16-P numerics).
__device__ inline float build_pa(const f32x16& S, s16x8& f0, s16x8& f1) {
    unsigned w[8];
    #pragma unroll
    for (int e = 0; e < 8; e++)
        w[e] = pkbf(__expf(S[2 * e]), __expf(S[2 * e + 1]));
    float ls = 0.f;
    #pragma unroll
    for (int e = 0; e < 8; e++)
        ls += __uint_as_float(w[e] << 16) + __uint_as_float(w[e] & 0xFFFF0000u);
    // lane l holds p[reg] = P[q=l&31][j=(reg&3)+8*(reg>>2)+4*(l>>5)].
    // Exchange with partner lane (same q, other h) to get contiguous-k frags:
    plswap(w[0], w[2]);   // -> frag0 words 0,2
    plswap(w[1], w[3]);   // -> frag0 words 1,3
    plswap(w[4], w[6]);   // -> frag1 words 0,2
    plswap(w[5], w[7]);   // -> frag1 words 1,3
    union { unsigned u[4]; s16x8 v; } A, B;
    A.u[0] = w[0]; A.u[1] = w[1]; A.u[2] = w[2]; A.u[3] = w[3];
    B.u[0] = w[4]; B.u[1] = w[5]; B.u[2] = w[6]; B.u[3] = w[7];
    f0 = A.v; f1 = B.v;
    return ls;
}

__global__ __launch_bounds__(256, 2) void attn_mfma_kernel(
    const ushort* __restrict__ qn,   // [B][N][CI]
    const ushort* __restrict__ kn,   // [B][N][CI]
    const ushort* __restrict__ vm,   // [B][CI][N]
    ushort* __restrict__ Opart,      // [4][B][N][CI] bf16 (unnormalized)
    float* __restrict__ lbuf)        // [4][B][N] row sums
{
    __shared__ __align__(16) ushort smem[17920];   // 35840 B
    ushort* Ks = smem;                 // [64][SQK]  = 8704 elems
    ushort* Vt = smem + 8704;          // [128][SPV] = 9216 elems

    const int b     = blockIdx.z;
    const int chunk = blockIdx.y;
    const int i0    = blockIdx.x * 128;
    const int jbase = chunk * JCHUNK;
    const int t     = threadIdx.x;
    const int wv    = t >> 6;
    const int lane  = t & 63;
    const int n32   = lane & 31;
    const int h     = lane >> 5;

    const ushort* qb = qn + ((size_t)b * N_ + i0) * CI_;
    const ushort* kb = kn + (size_t)b * N_ * CI_;
    const ushort* vb = vm + (size_t)b * CI_ * N_;

    // ---- Q fragments straight from global: lane's q-row = 32*wv + n32.
    // (Same per-lane layout serves as MFMA B-operand in the swapped QK^T.)
    s16x8 aQ[8];
    #pragma unroll
    for (int kk = 0; kk < 8; kk++)
        aQ[kk] = *(const s16x8*)&qb[(size_t)(32 * wv + n32) * CI_ + 16 * kk + 8 * h];

    f32x16 Oacc[4];
    #pragma unroll
    for (int dt = 0; dt < 4; dt++)
        #pragma unroll
        for (int e = 0; e < 16; e++) Oacc[dt][e] = 0.f;
    float lsum = 0.f;

    // ---- prefetch first j-tile (K: 64x128, V: 128x64 -> 4+4 uint4/thread)
    uint4 pfK[4], pfV[4];
    #pragma unroll
    for (int r = 0; r < 4; r++) {
        int idx = t + 256 * r;
        int row = idx >> 4, ch = idx & 15;
        pfK[r] = *(const uint4*)&kb[(size_t)(jbase + row) * CI_ + ch * 8];
    }
    #pragma unroll
    for (int r = 0; r < 4; r++) {
        int idx = t + 256 * r;
        int d = idx >> 3, ch = idx & 7;
        pfV[r] = *(const uint4*)&vb[(size_t)d * N_ + jbase + ch * 8];
    }

    for (int jt = jbase; jt < jbase + JCHUNK; jt += 64) {
        block_sync_lds();   // prev tile's LDS reads retired in all waves
        // commit prefetched tile (compiler inserts the data-arrival vmcnt here)
        #pragma unroll
        for (int r = 0; r < 4; r++) {
            int idx = t + 256 * r;
            int row = idx >> 4, ch = idx & 15;
            *(uint4*)&Ks[row * SQK + ch * 8] = pfK[r];
        }
        #pragma unroll
        for (int r = 0; r < 4; r++) {
            int idx = t + 256 * r;
            int d = idx >> 3, ch = idx & 7;
            *(uint4*)&Vt[d * SPV + ch * 8] = pfV[r];
        }
        block_sync_lds();   // K/V visible; no vm drain

        // prefetch next tile; stays in flight until next commit
        if (jt + 64 < jbase + JCHUNK) {
            const ushort* ksrc = kb + (size_t)(jt + 64) * CI_;
            #pragma unroll
            for (int r = 0; r < 4; r++) {
                int idx = t + 256 * r;
                int row = idx >> 4, ch = idx & 15;
                pfK[r] = *(const uint4*)&ksrc[(size_t)row * CI_ + ch * 8];
            }
            #pragma unroll
            for (int r = 0; r < 4; r++) {
                int idx = t + 256 * r;
                int d = idx >> 3, ch = idx & 7;
                pfV[r] = *(const uint4*)&vb[(size_t)d * N_ + jt + 64 + ch * 8];
            }
        }

        // ---- S^T = (Q K^T)^T per j-subtile: mfma(A=K rows j, B=Q cols q).
        // D[m=j][n=q]: lane holds its q = n32, 16 j-values in regs.
        f32x16 S0, S1;
        #pragma unroll
        for (int e = 0; e < 16; e++) { S0[e] = 0.f; S1[e] = 0.f; }
        __builtin_amdgcn_s_setprio(1);
        #pragma unroll
        for (int kk = 0; kk < 8; kk++) {
            s16x8 aK0 = *(const s16x8*)&Ks[n32 * SQK + 16 * kk + 8 * h];
            s16x8 aK1 = *(const s16x8*)&Ks[(32 + n32) * SQK + 16 * kk + 8 * h];
            S0 = __builtin_amdgcn_mfma_f32_32x32x16_bf16(aK0, aQ[kk], S0, 0, 0, 0);
            S1 = __builtin_amdgcn_mfma_f32_32x32x16_bf16(aK1, aQ[kk], S1, 0, 0, 0);
        }
        __builtin_amdgcn_s_setprio(0);

        // ---- in-register P = exp(S^T): build 4 PV A-frags + row-sum
        s16x8 pa[4];
        lsum += build_pa(S0, pa[0], pa[1]);   // j 0..31  -> k-slots 0,1
        lsum += build_pa(S1, pa[2], pa[3]);   // j 32..63 -> k-slots 2,3

        // ---- PV: O[32q x 128d] += P[32q x 64j] V[64j x 128d]
        __builtin_amdgcn_s_setprio(1);
        #pragma unroll
        for (int dt = 0; dt < 4; dt++) {
            #pragma unroll
            for (int kk = 0; kk < 4; kk++) {
                s16x8 bV = *(const s16x8*)&Vt[(32 * dt + n32) * SPV + 16 * kk + 8 * h];
                Oacc[dt] = __builtin_amdgcn_mfma_f32_32x32x16_bf16(pa[kk], bV, Oacc[dt], 0, 0, 0);
            }
        }
        __builtin_amdgcn_s_setprio(0);
    }

    // ---- epilogue: unnormalized O -> [b][n][d] bf16; l -> lbuf
    ushort* Ob = Opart + (size_t)chunk * (B_ * N_ * CI_) + ((size_t)b * N_ + i0) * CI_;
    #pragma unroll
    for (int rg = 0; rg < 16; rg++) {
        int R = (rg & 3) + 8 * (rg >> 2) + 4 * h;
        int q = 32 * wv + R;
        #pragma unroll
        for (int dt = 0; dt < 4; dt++)
            Ob[(size_t)q * CI_ + 32 * dt + n32] = f2bf(Oacc[dt][rg]);
    }
    // each lane's lsum covers its q = n32 for one h-half of j; combine halves
    float ot  = __shfl_xor(lsum, 32);
    float tot = lsum + ot;
    if (h == 0)
        lbuf[((size_t)chunk * B_ + b) * N_ + i0 + 32 * wv + n32] = tot;
}

// ---------------------------------------------------------------------------
// Output GEMM (bf16 MFMA) with fused 4-chunk combine in staging:
//   y[n][d] = (O0+O1+O2+O3)[n][d] / (l0+l1+l2+l3)[n]
//   out[b,m,n] = sum_d Wo[m,d]*y[n][d] + bo[m] + x[b,m,n]
// ---------------------------------------------------------------------------
__global__ __launch_bounds__(256) void outgemm_kernel(
    const ushort* __restrict__ Wobf, const float* __restrict__ bo,
    const ushort* __restrict__ Opart, const float* __restrict__ lbuf,
    const float* __restrict__ x, float* __restrict__ out)
{
    __shared__ ushort Ws[64][72];
    __shared__ ushort Ys[64][72];
    const int b = blockIdx.z, m0 = blockIdx.y * 64, n0 = blockIdx.x * 64;
    const int t = threadIdx.x, wv = t >> 6, lane = t & 63;
    const int g4 = lane >> 4, ln = lane & 15;
    const ushort* Wsrc = Wobf + (size_t)m0 * CI_;
    const size_t cs = (size_t)B_ * N_ * CI_;   // chunk stride

    f32x4 acc[4];
    #pragma unroll
    for (int i = 0; i < 4; i++) acc[i] = (f32x4){0.f, 0.f, 0.f, 0.f};

    for (int k0 = 0; k0 < CI_; k0 += 64) {
        block_sync_lds();
        #pragma unroll
        for (int r = 0; r < 2; r++) {
            int idx = t + 256 * r;
            int row = idx >> 3, k8 = (idx & 7) * 8;
            *(uint4*)&Ws[row][k8] = *(const uint4*)&Wsrc[(size_t)row * CI_ + k0 + k8];
            // fused combine: Y = (O0+O1+O2+O3) / (l0+l1+l2+l3)
            size_t obase = ((size_t)b * N_ + n0 + row) * CI_ + k0 + k8;
            float lsum = 0.f;
            #pragma unroll
            for (int c = 0; c < 4; c++)
                lsum += lbuf[((size_t)c * B_ + b) * N_ + n0 + row];
            float inv = 1.0f / lsum;
            ushort o0[8], o1[8], o2[8], o3[8], yo[8];
            *(uint4*)o0 = *(const uint4*)&Opart[obase];
            *(uint4*)o1 = *(const uint4*)&Opart[cs + obase];
            *(uint4*)o2 = *(const uint4*)&Opart[2 * cs + obase];
            *(uint4*)o3 = *(const uint4*)&Opart[3 * cs + obase];
            #pragma unroll
            for (int u = 0; u < 8; u++)
                yo[u] = f2bf((bf2f(o0[u]) + bf2f(o1[u]) + bf2f(o2[u]) + bf2f(o3[u])) * inv);
            *(uint4*)&Ys[row][k8] = *(uint4*)yo;
        }
        block_sync_lds();
        #pragma unroll
        for (int kk = 0; kk < 2; kk++) {
            s16x8 aW = *(const s16x8*)&Ws[16 * wv + ln][32 * kk + 8 * g4];
            #pragma unroll
            for (int nt = 0; nt < 4; nt++) {
                s16x8 bY = *(const s16x8*)&Ys[16 * nt + ln][32 * kk + 8 * g4];
                acc[nt] = __builtin_amdgcn_mfma_f32_16x16x32_bf16(aW, bY, acc[nt], 0, 0, 0);
            }
        }
    }

    float* outb = out + (size_t)b * C_ * N_;
    const float* xb = x + (size_t)b * C_ * N_;
    #pragma unroll
    for (int r = 0; r < 4; r++) {
        int m = m0 + 16 * wv + 4 * g4 + r;
        float bi = bo[m];
        #pragma unroll
        for (int nt = 0; nt < 4; nt++) {
            size_t idx = (size_t)m * N_ + n0 + 16 * nt + ln;
            outb[idx] = acc[nt][r] + bi + xb[idx];
        }
    }
}

// ---------------------------------------------------------------------------
extern "C" void kernel_launch(void* const* d_in, const int* in_sizes, int n_in,
                              void* d_out, int out_size, void* d_ws, size_t ws_size,
                              hipStream_t stream) {
    const float* x  = (const float*)d_in[0];
    const float* Wg = (const float*)d_in[1];
    const float* bg = (const float*)d_in[2];
    const float* Wt = (const float*)d_in[3];
    const float* bt = (const float*)d_in[4];
    const float* Wp = (const float*)d_in[5];
    const float* bp = (const float*)d_in[6];
    const float* Wo = (const float*)d_in[7];
    const float* bo = (const float*)d_in[8];
    float* out = (float*)d_out;

    // ws layout (bytes). xT (8 MB) dead after proj; Opart (16 MB) aliases it.
    char* w = (char*)d_ws;
    ushort* xT    = (ushort*)w;                   // [B][N][C]  bf16, 8 MB
    ushort* Opart = (ushort*)w;                   // [4][B][N][CI] bf16, 16 MB
    ushort* g     = (ushort*)(w + 16777216);      // [B][CI][N] bf16, 4 MB
    ushort* tht   = (ushort*)(w + 20971520);      // [B][N][CI] bf16, 4 MB
    ushort* pht   = (ushort*)(w + 25165824);      // [B][N][CI] bf16, 4 MB
    ushort* Wcat  = (ushort*)(w + 29360128);      // [384][256] bf16
    ushort* Wobf  = (ushort*)(w + 29556736);      // [256][128] bf16
    float*  bcat  = (float*) (w + 29622272);      // [384]
    float*  lbuf  = (float*) (w + 29623808);      // [4][B][N] fp32, 256 KB

    dim3 blk(256);
    wcast_kernel<<<512, blk, 0, stream>>>(Wg, Wt, Wp, Wo, bg, bt, bp, Wcat, Wobf, bcat);
    xt_kernel<<<dim3(N_ / 64, C_ / 64, B_), blk, 0, stream>>>(x, xT);
    proj_kernel<<<dim3(N_ / 64, 6, B_), blk, 0, stream>>>(Wcat, bcat, xT, g, tht, pht);
    attn_mfma_kernel<<<dim3(N_ / 128, 4, B_), blk, 0, stream>>>(tht, pht, g, Opart, lbuf);
    outgemm_kernel<<<dim3(N_ / 64, C_ / 64, B_), blk, 0, stream>>>(Wobf, bo, Opart, lbuf, x, out);
}

// Round 2
// 156.186 us; speedup vs baseline: 1.2573x; 1.2176x over previous
//
#include <hip/hip_runtime.h>
#include <math.h>

// Problem constants (fixed by the reference):
#define B_  4
#define C_  256     // in/out channels
#define CI_ 128     // inter channels (attention head dim D)
#define N_  4096    // H*W

typedef short s16x8  __attribute__((ext_vector_type(8)));    // 8 bf16 (4 VGPRs)
typedef float f32x4  __attribute__((ext_vector_type(4)));    // 16x16 accumulator
typedef float f32x16 __attribute__((ext_vector_type(16)));   // 32x32 accumulator

// fp32 -> bf16 (RNE)
__device__ inline ushort f2bf(float f) {
    unsigned int u = __float_as_uint(f);
    u += 0x7FFF + ((u >> 16) & 1);
    return (ushort)(u >> 16);
}
__device__ inline float bf2f(ushort u) {
    return __uint_as_float(((unsigned int)u) << 16);
}

// packed f32x2 -> bf16x2 (RNE), dst[15:0]=bf16(a), dst[31:16]=bf16(b)
__device__ inline unsigned pkbf(float a, float b) {
    unsigned r;
    asm("v_cvt_pk_bf16_f32 %0, %1, %2" : "=v"(r) : "v"(a), "v"(b));
    return r;
}
// v_permlane32_swap_b32 x, y:
//   new x[32+i] = old y[i];  new y[i] = old x[32+i]   (i = 0..31)
__device__ inline void plswap(unsigned &x, unsigned &y) {
    asm volatile("v_permlane32_swap_b32 %0, %1" : "+v"(x), "+v"(y));
}

// Direct global->LDS DMA, 16B per lane. LDS dest is wave-uniform base +
// lane*16 (linear); swizzling is done on the per-lane GLOBAL source address
// (m201 both-sides pattern).
__device__ inline void gload_lds16(const void* g, void* l) {
    __builtin_amdgcn_global_load_lds(
        (const __attribute__((address_space(1))) unsigned int*)g,
        (__attribute__((address_space(3))) unsigned int*)l, 16, 0, 0);
}

// LDS-only workgroup sync: waits DS-queue drain (lgkmcnt) + rendezvous,
// WITHOUT the vmcnt(0) drain __syncthreads() forces before s_barrier.
__device__ inline void block_sync_lds() {
    asm volatile("s_waitcnt lgkmcnt(0)" ::: "memory");
    __builtin_amdgcn_s_barrier();
    asm volatile("" ::: "memory");
}

// ---------------------------------------------------------------------------
// Weight cast: Wcat = [Wg;Wt;Wp] bf16 (384x256), Wobf bf16 (256x128),
// bcat = [bg;bt;bp] fp32 (384). Grid 512x256.
// ---------------------------------------------------------------------------
__global__ __launch_bounds__(256) void wcast_kernel(
    const float* __restrict__ Wg, const float* __restrict__ Wt,
    const float* __restrict__ Wp, const float* __restrict__ Wo,
    const float* __restrict__ bg, const float* __restrict__ bt,
    const float* __restrict__ bp,
    ushort* __restrict__ Wcat, ushort* __restrict__ Wobf,
    float* __restrict__ bcat)
{
    int i = blockIdx.x * 256 + threadIdx.x;
    if (i < 32768)       Wcat[i] = f2bf(Wg[i]);
    else if (i < 65536)  Wcat[i] = f2bf(Wt[i - 32768]);
    else if (i < 98304)  Wcat[i] = f2bf(Wp[i - 65536]);
    else if (i < 131072) Wobf[i - 98304] = f2bf(Wo[i - 98304]);
    if (i < 128)         bcat[i] = bg[i];
    else if (i < 256)    bcat[i] = bt[i - 128];
    else if (i < 384)    bcat[i] = bp[i - 256];
}

// ---------------------------------------------------------------------------
// x transpose+cast: x [B][C][N] fp32 -> xT [B][N][C] bf16. Tile 64c x 64n.
// ---------------------------------------------------------------------------
__global__ __launch_bounds__(256) void xt_kernel(
    const float* __restrict__ x, ushort* __restrict__ xT)
{
    __shared__ ushort Ls[64][72];
    const int b = blockIdx.z, c0 = blockIdx.y * 64, n0 = blockIdx.x * 64;
    const float* xb = x + ((size_t)b * C_ + c0) * N_ + n0;
    const int t = threadIdx.x;
    #pragma unroll
    for (int r = 0; r < 4; r++) {
        int idx = t + 256 * r;
        int c = idx >> 4, n4 = (idx & 15) * 4;
        float4 v = *(const float4*)&xb[(size_t)c * N_ + n4];
        ushort4 o;
        o.x = f2bf(v.x); o.y = f2bf(v.y); o.z = f2bf(v.z); o.w = f2bf(v.w);
        *(ushort4*)&Ls[c][n4] = o;
    }
    __syncthreads();
    ushort* xTb = xT + ((size_t)b * N_ + n0) * C_ + c0;
    #pragma unroll
    for (int r = 0; r < 2; r++) {
        int idx = t + 256 * r;
        int n = idx >> 3, c8 = (idx & 7) * 8;
        ushort tmp[8];
        #pragma unroll
        for (int u = 0; u < 8; u++) tmp[u] = Ls[c8 + u][n];
        *(uint4*)&xTb[(size_t)n * C_ + c8] = *(uint4*)tmp;
    }
}

// ---------------------------------------------------------------------------
// Fused projection GEMM (bf16 MFMA, 16x16x32). Grid (N/64, 6, B).
// ---------------------------------------------------------------------------
__global__ __launch_bounds__(256) void proj_kernel(
    const ushort* __restrict__ Wcat, const float* __restrict__ bcat,
    const ushort* __restrict__ xT,
    ushort* __restrict__ g, ushort* __restrict__ tht, ushort* __restrict__ pht)
{
    __shared__ ushort Ws[64][72];
    __shared__ ushort Xs[64][72];
    const int b = blockIdx.z, mt = blockIdx.y, n0 = blockIdx.x * 64;
    const int t = threadIdx.x, wv = t >> 6, lane = t & 63;
    const int g4 = lane >> 4, ln = lane & 15;
    const ushort* Wsrc = Wcat + (size_t)mt * 64 * C_;
    const ushort* Xsrc = xT + ((size_t)b * N_ + n0) * C_;

    f32x4 acc[4];
    #pragma unroll
    for (int i = 0; i < 4; i++) acc[i] = (f32x4){0.f, 0.f, 0.f, 0.f};

    for (int k0 = 0; k0 < C_; k0 += 64) {
        block_sync_lds();
        #pragma unroll
        for (int r = 0; r < 2; r++) {
            int idx = t + 256 * r;
            int row = idx >> 3, k8 = (idx & 7) * 8;
            *(uint4*)&Ws[row][k8] = *(const uint4*)&Wsrc[(size_t)row * C_ + k0 + k8];
            *(uint4*)&Xs[row][k8] = *(const uint4*)&Xsrc[(size_t)row * C_ + k0 + k8];
        }
        block_sync_lds();
        if (mt < 2) {
            #pragma unroll
            for (int kk = 0; kk < 2; kk++) {
                s16x8 aW = *(const s16x8*)&Ws[16 * wv + ln][32 * kk + 8 * g4];
                #pragma unroll
                for (int nt = 0; nt < 4; nt++) {
                    s16x8 bX = *(const s16x8*)&Xs[16 * nt + ln][32 * kk + 8 * g4];
                    acc[nt] = __builtin_amdgcn_mfma_f32_16x16x32_bf16(aW, bX, acc[nt], 0, 0, 0);
                }
            }
        } else {
            #pragma unroll
            for (int kk = 0; kk < 2; kk++) {
                s16x8 aX = *(const s16x8*)&Xs[16 * wv + ln][32 * kk + 8 * g4];
                #pragma unroll
                for (int ct = 0; ct < 4; ct++) {
                    s16x8 bW = *(const s16x8*)&Ws[16 * ct + ln][32 * kk + 8 * g4];
                    acc[ct] = __builtin_amdgcn_mfma_f32_16x16x32_bf16(aX, bW, acc[ct], 0, 0, 0);
                }
            }
        }
    }

    if (mt < 2) {
        ushort* ob = g + (size_t)b * CI_ * N_;
        #pragma unroll
        for (int r = 0; r < 4; r++) {
            int mloc = 16 * wv + 4 * g4 + r;
            float bi = bcat[mt * 64 + mloc];
            #pragma unroll
            for (int nt = 0; nt < 4; nt++)
                ob[(size_t)(mt * 64 + mloc) * N_ + n0 + 16 * nt + ln] = f2bf(acc[nt][r] + bi);
        }
    } else {
        ushort* ob = ((mt < 4) ? tht : pht) + (size_t)b * N_ * CI_;
        int cib = ((mt - 2) & 1) * 64;
        #pragma unroll
        for (int r = 0; r < 4; r++) {
            int nloc = 16 * wv + 4 * g4 + r;
            #pragma unroll
            for (int ct = 0; ct < 4; ct++) {
                float bi = bcat[mt * 64 + 16 * ct + ln];
                ob[(size_t)(n0 + nloc) * CI_ + cib + 16 * ct + ln] = f2bf(acc[ct][r] + bi);
            }
        }
    }
}

// ---------------------------------------------------------------------------
// MFMA flash attention, 32x32x16, in-register softmax (T12), direct
// global->LDS K/V staging (T2 both-sides XOR swizzle), XCD-chunked block
// swizzle (T1). Single-buffered LDS; the per-tile vmcnt(0) stall is hidden
// by cross-block TLP (3+ blocks/CU: regs cut by dropping reg-prefetch and
// serializing S0/S1 softmax).
// Template NC = number of j-chunks (grid.y); JCHUNK = N_/NC.
// ---------------------------------------------------------------------------

// Build two PV A-fragments from the 16 in-lane scores of one 32-j S^T tile.
__device__ inline float build_pa(const f32x16& S, s16x8& f0, s16x8& f1) {
    unsigned w[8];
    #pragma unroll
    for (int e = 0; e < 8; e++)
        w[e] = pkbf(__expf(S[2 * e]), __expf(S[2 * e + 1]));
    float ls = 0.f;
    #pragma unroll
    for (int e = 0; e < 8; e++)
        ls += __uint_as_float(w[e] << 16) + __uint_as_float(w[e] & 0xFFFF0000u);
    // lane l holds p[reg] = P[q=l&31][j=(reg&3)+8*(reg>>2)+4*(l>>5)].
    plswap(w[0], w[2]);
    plswap(w[1], w[3]);
    plswap(w[4], w[6]);
    plswap(w[5], w[7]);
    union { unsigned u[4]; s16x8 v; } A, B;
    A.u[0] = w[0]; A.u[1] = w[1]; A.u[2] = w[2]; A.u[3] = w[3];
    B.u[0] = w[4]; B.u[1] = w[5]; B.u[2] = w[6]; B.u[3] = w[7];
    f0 = A.v; f1 = B.v;
    return ls;
}

template <int NC>
__global__ __launch_bounds__(256, 3) void attn_mfma_kernel(
    const ushort* __restrict__ qn,   // [B][N][CI]
    const ushort* __restrict__ kn,   // [B][N][CI]
    const ushort* __restrict__ vm,   // [B][CI][N]
    ushort* __restrict__ Opart,      // [NC][B][N][CI] bf16 (unnormalized)
    float* __restrict__ lbuf)        // [NC][B][N] row sums
{
    constexpr int JC = N_ / NC;
    // K: [64][256B] linear+src-swizzled; V: [128][128B] linear+src-swizzled
    __shared__ __align__(16) char smemB[32768];
    char* KsB = smemB;
    char* VtB = smemB + 16384;

    // T1: XCD-bijective chunked swizzle so blocks sharing (b,chunk) K/V
    // co-locate on one XCD's L2. nb % 8 == 0 for NC in {4,8}.
    constexpr int NI = N_ / 128;
    constexpr int nb = NI * NC * B_;
    int flat = (blockIdx.z * NC + blockIdx.y) * NI + blockIdx.x;
    int nf   = (flat & 7) * (nb / 8) + (flat >> 3);
    const int i0    = (nf % NI) * 128;
    const int chunk = (nf / NI) % NC;
    const int b     = nf / (NI * NC);
    const int jbase = chunk * JC;

    const int t    = threadIdx.x;
    const int wv   = t >> 6;
    const int lane = t & 63;
    const int n32  = lane & 31;
    const int h    = lane >> 5;
    const int swz  = (n32 & 7) << 4;   // reader-side XOR swizzle

    const ushort* qb = qn + ((size_t)b * N_ + i0) * CI_;
    const char* kB = (const char*)(kn + (size_t)b * N_ * CI_);
    const char* vB = (const char*)(vm + (size_t)b * CI_ * N_);

    // ---- Q fragments straight from global: lane's q-row = 32*wv + n32.
    s16x8 aQ[8];
    #pragma unroll
    for (int kk = 0; kk < 8; kk++)
        aQ[kk] = *(const s16x8*)(qb + (size_t)(32 * wv + n32) * CI_ + 16 * kk + 8 * h);

    f32x16 Oacc[4];
    #pragma unroll
    for (int dt = 0; dt < 4; dt++)
        #pragma unroll
        for (int e = 0; e < 16; e++) Oacc[dt][e] = 0.f;
    float lsum = 0.f;

    // stager per-lane constants
    const int kr = lane >> 4;            // K: row within 4-row chunk
    const int kc = (lane & 15) << 4;     // K: byte col 0..255
    const int vr = lane >> 3;            // V: row within 8-row chunk
    const int vc = (lane & 7) << 4;      // V: byte col 0..127

    for (int jt = jbase; jt < jbase + JC; jt += 64) {
        block_sync_lds();   // all waves done reading prev tile's LDS

        // ---- stage K (16KB) + V (16KB): 4+4 DMA chunks of 1024B per wave.
        // LDS linear; global source pre-swizzled: src_col ^= (row&7)<<4.
        #pragma unroll
        for (int r = 0; r < 4; r++) {
            int c   = (wv << 2) + r;
            int row = (c << 2) + kr;                       // 0..63
            int src = ((jt + row) << 8) + (kc ^ ((row & 7) << 4));
            gload_lds16(kB + src, KsB + (c << 10));
        }
        #pragma unroll
        for (int r = 0; r < 4; r++) {
            int c   = (wv << 2) + r;
            int row = (c << 3) + vr;                       // 0..127
            int src = row * (N_ * 2) + (jt << 1) + (vc ^ ((row & 7) << 4));
            gload_lds16(vB + src, VtB + (c << 10));
        }
        asm volatile("s_waitcnt vmcnt(0)" ::: "memory");
        __builtin_amdgcn_s_barrier();   // K/V visible to all waves

        // ---- S0^T = K[0:32] Q^T (8-MFMA chain), then softmax0 (S0 dies)
        s16x8 pa[4];
        f32x16 S0;
        #pragma unroll
        for (int e = 0; e < 16; e++) S0[e] = 0.f;
        __builtin_amdgcn_s_setprio(1);
        #pragma unroll
        for (int kk = 0; kk < 8; kk++) {
            s16x8 aK0 = *(const s16x8*)(KsB + (n32 << 8) + (((kk << 5) + (h << 4)) ^ swz));
            S0 = __builtin_amdgcn_mfma_f32_32x32x16_bf16(aK0, aQ[kk], S0, 0, 0, 0);
        }
        __builtin_amdgcn_s_setprio(0);
        lsum += build_pa(S0, pa[0], pa[1]);   // j 0..31 -> k-slots 0,1

        // ---- S1^T = K[32:64] Q^T, then softmax1
        f32x16 S1;
        #pragma unroll
        for (int e = 0; e < 16; e++) S1[e] = 0.f;
        __builtin_amdgcn_s_setprio(1);
        #pragma unroll
        for (int kk = 0; kk < 8; kk++) {
            s16x8 aK1 = *(const s16x8*)(KsB + 8192 + (n32 << 8) + (((kk << 5) + (h << 4)) ^ swz));
            S1 = __builtin_amdgcn_mfma_f32_32x32x16_bf16(aK1, aQ[kk], S1, 0, 0, 0);
        }
        __builtin_amdgcn_s_setprio(0);
        lsum += build_pa(S1, pa[2], pa[3]);   // j 32..63 -> k-slots 2,3

        // ---- PV: O[32q x 128d] += P[32q x 64j] V[64j x 128d]
        __builtin_amdgcn_s_setprio(1);
        #pragma unroll
        for (int dt = 0; dt < 4; dt++) {
            #pragma unroll
            for (int kk = 0; kk < 4; kk++) {
                s16x8 bV = *(const s16x8*)(VtB + ((32 * dt + n32) << 7)
                                               + (((kk << 5) + (h << 4)) ^ swz));
                Oacc[dt] = __builtin_amdgcn_mfma_f32_32x32x16_bf16(pa[kk], bV, Oacc[dt], 0, 0, 0);
            }
        }
        __builtin_amdgcn_s_setprio(0);
    }

    // ---- epilogue: unnormalized O -> [b][n][d] bf16; l -> lbuf
    ushort* Ob = Opart + (size_t)chunk * (B_ * N_ * CI_) + ((size_t)b * N_ + i0) * CI_;
    #pragma unroll
    for (int rg = 0; rg < 16; rg++) {
        int R = (rg & 3) + 8 * (rg >> 2) + 4 * h;
        int q = 32 * wv + R;
        #pragma unroll
        for (int dt = 0; dt < 4; dt++)
            Ob[(size_t)q * CI_ + 32 * dt + n32] = f2bf(Oacc[dt][rg]);
    }
    float ot  = __shfl_xor(lsum, 32);
    float tot = lsum + ot;
    if (h == 0)
        lbuf[((size_t)chunk * B_ + b) * N_ + i0 + 32 * wv + n32] = tot;
}

// ---------------------------------------------------------------------------
// Output GEMM (bf16 MFMA) with fused NC-chunk combine in staging:
//   y[n][d] = (sum_c Oc)[n][d] / (sum_c lc)[n]
//   out[b,m,n] = sum_d Wo[m,d]*y[n][d] + bo[m] + x[b,m,n]
// ---------------------------------------------------------------------------
template <int NC>
__global__ __launch_bounds__(256) void outgemm_kernel(
    const ushort* __restrict__ Wobf, const float* __restrict__ bo,
    const ushort* __restrict__ Opart, const float* __restrict__ lbuf,
    const float* __restrict__ x, float* __restrict__ out)
{
    __shared__ ushort Ws[64][72];
    __shared__ ushort Ys[64][72];
    const int b = blockIdx.z, m0 = blockIdx.y * 64, n0 = blockIdx.x * 64;
    const int t = threadIdx.x, wv = t >> 6, lane = t & 63;
    const int g4 = lane >> 4, ln = lane & 15;
    const ushort* Wsrc = Wobf + (size_t)m0 * CI_;
    const size_t cs = (size_t)B_ * N_ * CI_;   // chunk stride

    f32x4 acc[4];
    #pragma unroll
    for (int i = 0; i < 4; i++) acc[i] = (f32x4){0.f, 0.f, 0.f, 0.f};

    for (int k0 = 0; k0 < CI_; k0 += 64) {
        block_sync_lds();
        #pragma unroll
        for (int r = 0; r < 2; r++) {
            int idx = t + 256 * r;
            int row = idx >> 3, k8 = (idx & 7) * 8;
            *(uint4*)&Ws[row][k8] = *(const uint4*)&Wsrc[(size_t)row * CI_ + k0 + k8];
            // fused combine: Y = (sum_c Oc) / (sum_c lc)
            size_t obase = ((size_t)b * N_ + n0 + row) * CI_ + k0 + k8;
            float lsum = 0.f;
            #pragma unroll
            for (int c = 0; c < NC; c++)
                lsum += lbuf[((size_t)c * B_ + b) * N_ + n0 + row];
            float inv = 1.0f / lsum;
            float osum[8];
            #pragma unroll
            for (int u = 0; u < 8; u++) osum[u] = 0.f;
            #pragma unroll
            for (int c = 0; c < NC; c++) {
                ushort oc[8];
                *(uint4*)oc = *(const uint4*)&Opart[(size_t)c * cs + obase];
                #pragma unroll
                for (int u = 0; u < 8; u++) osum[u] += bf2f(oc[u]);
            }
            ushort yo[8];
            #pragma unroll
            for (int u = 0; u < 8; u++) yo[u] = f2bf(osum[u] * inv);
            *(uint4*)&Ys[row][k8] = *(uint4*)yo;
        }
        block_sync_lds();
        #pragma unroll
        for (int kk = 0; kk < 2; kk++) {
            s16x8 aW = *(const s16x8*)&Ws[16 * wv + ln][32 * kk + 8 * g4];
            #pragma unroll
            for (int nt = 0; nt < 4; nt++) {
                s16x8 bY = *(const s16x8*)&Ys[16 * nt + ln][32 * kk + 8 * g4];
                acc[nt] = __builtin_amdgcn_mfma_f32_16x16x32_bf16(aW, bY, acc[nt], 0, 0, 0);
            }
        }
    }

    float* outb = out + (size_t)b * C_ * N_;
    const float* xb = x + (size_t)b * C_ * N_;
    #pragma unroll
    for (int r = 0; r < 4; r++) {
        int m = m0 + 16 * wv + 4 * g4 + r;
        float bi = bo[m];
        #pragma unroll
        for (int nt = 0; nt < 4; nt++) {
            size_t idx = (size_t)m * N_ + n0 + 16 * nt + ln;
            outb[idx] = acc[nt][r] + bi + xb[idx];
        }
    }
}

// ---------------------------------------------------------------------------
extern "C" void kernel_launch(void* const* d_in, const int* in_sizes, int n_in,
                              void* d_out, int out_size, void* d_ws, size_t ws_size,
                              hipStream_t stream) {
    const float* x  = (const float*)d_in[0];
    const float* Wg = (const float*)d_in[1];
    const float* bg = (const float*)d_in[2];
    const float* Wt = (const float*)d_in[3];
    const float* bt = (const float*)d_in[4];
    const float* Wp = (const float*)d_in[5];
    const float* bp = (const float*)d_in[6];
    const float* Wo = (const float*)d_in[7];
    const float* bo = (const float*)d_in[8];
    float* out = (float*)d_out;

    // NC=8 needs 46,925,312 B of workspace; fall back to NC=4 (29.9 MB)
    // if the harness workspace is smaller.
    const bool big = ws_size >= 46925312ull;
    const int NC = big ? 8 : 4;

    char* w = (char*)d_ws;
    size_t opart_sz = (size_t)NC * B_ * N_ * CI_ * sizeof(ushort);
    ushort* xT    = (ushort*)w;                        // [B][N][C] bf16, 8MB (dead after proj)
    ushort* Opart = (ushort*)w;                        // [NC][B][N][CI] bf16 (aliases xT)
    ushort* g     = (ushort*)(w + opart_sz);           // [B][CI][N] bf16, 4MB
    ushort* tht   = (ushort*)(w + opart_sz + 4194304); // [B][N][CI] bf16, 4MB
    ushort* pht   = (ushort*)(w + opart_sz + 8388608); // [B][N][CI] bf16, 4MB
    ushort* Wcat  = (ushort*)(w + opart_sz + 12582912);          // [384][256] bf16
    ushort* Wobf  = (ushort*)(w + opart_sz + 12582912 + 196608); // [256][128] bf16
    float*  bcat  = (float*) (w + opart_sz + 12582912 + 262144); // [384]
    float*  lbuf  = (float*) (w + opart_sz + 12582912 + 263680); // [NC][B][N] fp32

    dim3 blk(256);
    wcast_kernel<<<512, blk, 0, stream>>>(Wg, Wt, Wp, Wo, bg, bt, bp, Wcat, Wobf, bcat);
    xt_kernel<<<dim3(N_ / 64, C_ / 64, B_), blk, 0, stream>>>(x, xT);
    proj_kernel<<<dim3(N_ / 64, 6, B_), blk, 0, stream>>>(Wcat, bcat, xT, g, tht, pht);
    if (big) {
        attn_mfma_kernel<8><<<dim3(N_ / 128, 8, B_), blk, 0, stream>>>(tht, pht, g, Opart, lbuf);
        outgemm_kernel<8><<<dim3(N_ / 64, C_ / 64, B_), blk, 0, stream>>>(Wobf, bo, Opart, lbuf, x, out);
    } else {
        attn_mfma_kernel<4><<<dim3(N_ / 128, 4, B_), blk, 0, stream>>>(tht, pht, g, Opart, lbuf);
        outgemm_kernel<4><<<dim3(N_ / 64, C_ / 64, B_), blk, 0, stream>>>(Wobf, bo, Opart, lbuf, x, out);
    }
}